// Round 1
// baseline (3285.278 us; speedup 1.0000x reference)
//
#include <hip/hip_runtime.h>
#include <hip/hip_bf16.h>
#include <hip/hip_fp16.h>

#define T_ 512
#define B_ 128
#define E_ 256
#define H_ 256

typedef _Float16 h8 __attribute__((ext_vector_type(8)));
typedef float    f4 __attribute__((ext_vector_type(4)));
typedef unsigned u4 __attribute__((ext_vector_type(4)));

// ---------------------------------------------------------------------------
// K1: embedding gather + fp32->fp16, MFMA A-fragment order:
// h8 index = (t*64 + grp*8 + kb)*64 + lane, holding
// x[t][b = grp*16 + (lane&15)][e = kb*32 + (lane>>4)*8 + j], j=0..7
// ---------------------------------------------------------------------------
__global__ __launch_bounds__(256) void k_gather(const int* __restrict__ tok,
        const float* __restrict__ emb, _Float16* __restrict__ x16)
{
    const int t = blockIdx.x;
    const int tid = threadIdx.x;
    const int wave = tid >> 6, lane = tid & 63;
    const int q = lane >> 4, l16 = lane & 15;
    __shared__ int rows[B_];
    if (tid < B_) rows[tid] = tok[(size_t)tid * T_ + t];
    __syncthreads();
    for (int it = 0; it < 16; ++it) {
        int pair = it * 4 + wave;          // pair = grp*8 + kb
        int grp = pair >> 3, kb = pair & 7;
        int b = grp * 16 + l16;
        int e = kb * 32 + q * 8;
        const float* src = emb + (size_t)rows[b] * E_ + e;
        float4 a = *(const float4*)src;
        float4 c = *(const float4*)(src + 4);
        h8 hv;
        hv[0]=(_Float16)a.x; hv[1]=(_Float16)a.y; hv[2]=(_Float16)a.z; hv[3]=(_Float16)a.w;
        hv[4]=(_Float16)c.x; hv[5]=(_Float16)c.y; hv[6]=(_Float16)c.z; hv[7]=(_Float16)c.w;
        *(h8*)(x16 + (((size_t)t * 64 + pair) * 64 + lane) * 8) = hv;
    }
}

// ---------------------------------------------------------------------------
// K2: weight permute+convert to fp16 B-fragment layout.
// wp element [(d*32 + mat*16 + p*4 + w)*16384 + nt*4096 + n*256 + k] =
//   M[k][nt*256 + p*64 + w*16 + n],  M = (mat? U : W) of direction d.
// One block per (d, mat, p, w) = 64 blocks.
// ---------------------------------------------------------------------------
__global__ __launch_bounds__(256) void k_perm(const float* __restrict__ Wf, const float* __restrict__ Uf,
        const float* __restrict__ Wb, const float* __restrict__ Ub, _Float16* __restrict__ wp)
{
    const int bid = blockIdx.x;
    const int d = bid >> 5, mat = (bid >> 4) & 1, p = (bid >> 2) & 3, w = bid & 3;
    const float* src = d ? (mat ? Ub : Wb) : (mat ? Uf : Wf);
    _Float16* dst = wp + (size_t)bid * 16384;
    const int tid = threadIdx.x;
    const int cbase = p * 64 + w * 16;
    __shared__ float S[256][17];
    for (int nt = 0; nt < 4; ++nt) {
        for (int it = 0; it < 16; ++it) {
            int idx = it * 256 + tid;
            int k = idx >> 4, c16 = idx & 15;
            S[k][c16] = src[(size_t)k * 1024 + nt * 256 + cbase + c16];
        }
        __syncthreads();
        for (int it = 0; it < 16; ++it) {
            int idx = it * 256 + tid;
            int k = idx & 255, c16 = idx >> 8;
            dst[(size_t)nt * 4096 + c16 * 256 + k] = (_Float16)S[k][c16];
        }
        __syncthreads();
    }
}

// ---------------------------------------------------------------------------
// K3: fused recurrence. 64 WGs = (d, p quarter of units, grp of 16 rows);
// wave w owns 16 units (4 gates x 16 cols) with the FULL K=512 weight slice
// (W and U halves) pinned in VGPRs.
//
// v2 exchange: the 4 partner WGs (same d,grp; p=0..3) differ by blockIdx
// multiples of 8 -> same XCD under round-robin dispatch -> shared L2.
//  - each wave polls only ONE partner 64-unit block (4KB tagged dwords),
//    validates, and redistributes through an XOR-swizzled LDS tile;
//    own-WG units go to LDS directly (never through global).
//  - polls are sc0 (L1-bypass, L2-scope). Publishes are dual-stored:
//    sc0 (local L2 for co-located partners) + sc0 sc1 (write-through to
//    LLC). If a wave spins >512 rounds it permanently escalates to
//    sc0 sc1 polls -> worst case equals the old LLC-scope behavior, no hang.
//  - hx is memset to 0 each launch (kernel_launch) so stale tags from a
//    previous iteration can never satisfy a poll.
// ---------------------------------------------------------------------------
__device__ __forceinline__ float fsig(float x) {
    float t = __expf(-fabsf(x));
    float r = __builtin_amdgcn_rcpf(1.0f + t);
    return x >= 0.f ? r : 1.0f - r;
}
__device__ __forceinline__ float ftanh(float x) {
    float t = __expf(-2.0f * fabsf(x));
    float r = (1.0f - t) * __builtin_amdgcn_rcpf(1.0f + t);
    return x >= 0.f ? r : -r;
}

__global__ __launch_bounds__(256, 1) __attribute__((amdgpu_waves_per_eu(1, 1)))
void k_rnn(const _Float16* __restrict__ x16, const _Float16* __restrict__ wp,
           const float* __restrict__ bf, const float* __restrict__ bb,
           unsigned* __restrict__ hx, float* __restrict__ hfin)
{
    const int wg = blockIdx.x;           // 0..63 = d*32 + p*8 + grp
    const int d = wg >> 5;
    const int p = (wg >> 3) & 3;
    const int grp = wg & 7;
    const int tid = threadIdx.x;
    const int w = tid >> 6, lane = tid & 63;
    const int q = lane >> 4, l16 = lane & 15;

    // [parity 2][row 16][unit 256] fp16; column bytes XOR-swizzled by
    // ((row&7)<<4) so b128 reads/writes land 8 lanes per 16B slot (optimal).
    __shared__ char hsh[16384];

    // weights: wx (E half, k 0..255) + wu (H half): 64 h8 = 256 VGPRs
    h8 wx[4][8], wu[4][8];
    {
        const _Float16* bx = wp + (size_t)(d * 32 + 0  + p * 4 + w) * 16384;
        const _Float16* bu = wp + (size_t)(d * 32 + 16 + p * 4 + w) * 16384;
        #pragma unroll
        for (int nt = 0; nt < 4; ++nt)
            #pragma unroll
            for (int kb = 0; kb < 8; ++kb) {
                wx[nt][kb] = *(const h8*)(bx + nt * 4096 + l16 * 256 + kb * 32 + q * 8);
                wu[nt][kb] = *(const h8*)(bu + nt * 4096 + l16 * 256 + kb * 32 + q * 8);
            }
        #pragma unroll
        for (int nt = 0; nt < 4; ++nt)
            #pragma unroll
            for (int kb = 0; kb < 8; ++kb) {
                asm volatile("" : "+v"(wx[nt][kb]));
                asm volatile("" : "+v"(wu[nt][kb]));
            }
    }
    const float* bias = d ? bb : bf;
    float bv[4];
    #pragma unroll
    for (int g = 0; g < 4; ++g)
        bv[g] = bias[g * 256 + p * 64 + w * 16 + l16];

    unsigned* gbase = hx + (size_t)(d * 8 + grp) * 8192;  // [par 2][blk 4][row 16][unit 64]

    // x fragments for step 0
    h8 xf[8];
    {
        int xt = d ? (T_ - 1) : 0;
        const h8* xb = (const h8*)x16 + ((size_t)xt * 64 + grp * 8) * 64 + lane;
        #pragma unroll
        for (int kb = 0; kb < 8; ++kb) xf[kb] = xb[kb * 64];
    }

    float c4[4] = {0.f, 0.f, 0.f, 0.f};
    float hv4[4] = {0.f, 0.f, 0.f, 0.f};
    int llc_mode = 0;                    // sticky escalation flag (wave-uniform)
    const int swz = (l16 & 7) << 4;

    for (int s = 0; s < T_; ++s) {
        f4 acc[4];
        #pragma unroll
        for (int nt = 0; nt < 4; ++nt)
            acc[nt] = (f4){bv[nt], bv[nt], bv[nt], bv[nt]};
        // x @ W  (issues before the poll; hides exchange latency)
        #pragma unroll
        for (int kb = 0; kb < 8; ++kb)
            #pragma unroll
            for (int nt = 0; nt < 4; ++nt)
                acc[nt] = __builtin_amdgcn_mfma_f32_16x16x32_f16(xf[kb], wx[nt][kb], acc[nt], 0, 0, 0);
        __builtin_amdgcn_sched_barrier(0);   // keep x@W issued ahead of the poll

        if (s > 0) {
            const int par = (s - 1) & 1;
            char* lbase = hsh + par * 8192;
            // (a) own h_{s-1} -> LDS (16 units of this wave; never goes global
            //     for intra-WG consumers)
            {
                const int colb = (p * 64 + w * 16 + l16) * 2;
                #pragma unroll
                for (int r = 0; r < 4; ++r) {
                    const int row = q * 4 + r;
                    *(_Float16*)(lbase + row * 512 + (colb ^ ((row & 7) << 4))) = (_Float16)hv4[r];
                }
            }
            // (b) poll partner block w (w != p): 4 dwordx4 per lane = 4KB/wave
            if (w != p) {
                const unsigned etag = (unsigned)s << 16;
                const unsigned* pb = gbase + (size_t)par * 4096 + w * 1024 + l16 * 64 + q * 8;
                u4 pd[4];
                int spins = 0;
                while (true) {
                    if (!llc_mode) {
                        asm volatile("global_load_dwordx4 %0, %1, off sc0"            : "=v"(pd[0]) : "v"(pb) : "memory");
                        asm volatile("global_load_dwordx4 %0, %1, off offset:16 sc0"  : "=v"(pd[1]) : "v"(pb) : "memory");
                        asm volatile("global_load_dwordx4 %0, %1, off offset:128 sc0" : "=v"(pd[2]) : "v"(pb) : "memory");
                        asm volatile("global_load_dwordx4 %0, %1, off offset:144 sc0" : "=v"(pd[3]) : "v"(pb) : "memory");
                    } else {
                        asm volatile("global_load_dwordx4 %0, %1, off sc0 sc1"            : "=v"(pd[0]) : "v"(pb) : "memory");
                        asm volatile("global_load_dwordx4 %0, %1, off offset:16 sc0 sc1"  : "=v"(pd[1]) : "v"(pb) : "memory");
                        asm volatile("global_load_dwordx4 %0, %1, off offset:128 sc0 sc1" : "=v"(pd[2]) : "v"(pb) : "memory");
                        asm volatile("global_load_dwordx4 %0, %1, off offset:144 sc0 sc1" : "=v"(pd[3]) : "v"(pb) : "memory");
                    }
                    asm volatile("s_waitcnt vmcnt(0)"
                        : "+v"(pd[0]), "+v"(pd[1]), "+v"(pd[2]), "+v"(pd[3]) :: "memory");
                    unsigned bad = 0;
                    #pragma unroll
                    for (int j = 0; j < 4; ++j)
                        #pragma unroll
                        for (int e = 0; e < 4; ++e)
                            bad |= (pd[j][e] ^ etag) & 0xffff0000u;
                    if (__ballot(bad != 0) == 0ull) break;
                    if (++spins == 512) llc_mode = 1;   // sticky; never resets
                }
                // extract 16 halfs -> 2 h8 -> LDS (units w*64+q*8.. and +32)
                u4 h0, h1;
                h0[0] = (pd[0][0] & 0xffffu) | (pd[0][1] << 16);
                h0[1] = (pd[0][2] & 0xffffu) | (pd[0][3] << 16);
                h0[2] = (pd[1][0] & 0xffffu) | (pd[1][1] << 16);
                h0[3] = (pd[1][2] & 0xffffu) | (pd[1][3] << 16);
                h1[0] = (pd[2][0] & 0xffffu) | (pd[2][1] << 16);
                h1[1] = (pd[2][2] & 0xffffu) | (pd[2][3] << 16);
                h1[2] = (pd[3][0] & 0xffffu) | (pd[3][1] << 16);
                h1[3] = (pd[3][2] & 0xffffu) | (pd[3][3] << 16);
                const int cb0 = w * 128 + q * 16;
                *(u4*)(lbase + l16 * 512 + (cb0 ^ swz)) = h0;
                *(u4*)(lbase + l16 * 512 + ((cb0 + 64) ^ swz)) = h1;
            }
            __syncthreads();
            // (c) full h_{s-1} A-fragments from LDS, then h @ U
            h8 hf[8];
            #pragma unroll
            for (int kb = 0; kb < 8; ++kb)
                hf[kb] = *(const h8*)(lbase + l16 * 512 + ((kb * 64 + q * 16) ^ swz));
            #pragma unroll
            for (int kb = 0; kb < 8; ++kb)
                #pragma unroll
                for (int nt = 0; nt < 4; ++nt)
                    acc[nt] = __builtin_amdgcn_mfma_f32_16x16x32_f16(hf[kb], wu[nt][kb], acc[nt], 0, 0, 0);
        }
        // gates
        #pragma unroll
        for (int r = 0; r < 4; ++r) {
            float zi = acc[0][r];
            float zf = acc[1][r];
            float zg = acc[2][r];
            float zo = acc[3][r];
            float cn = fsig(zf) * c4[r] + fsig(zi) * ftanh(zg);
            c4[r] = cn;
            hv4[r] = fsig(zo) * ftanh(cn);
        }
        if (s < T_ - 1) {
            // publish h_s as tagged dwords: sc0 for co-XCD partners (L2),
            // sc0 sc1 write-through for the LLC fallback path
            const unsigned otag = (unsigned)(s + 1) << 16;
            unsigned* ob = gbase + (size_t)(s & 1) * 4096 + p * 1024 + w * 16 + l16;
            #pragma unroll
            for (int r = 0; r < 4; ++r) {
                _Float16 hh = (_Float16)hv4[r];
                unsigned v = otag | (unsigned)__builtin_bit_cast(unsigned short, hh);
                unsigned* addr = ob + (q * 4 + r) * 64;
                asm volatile("global_store_dword %0, %1, off sc0"     :: "v"(addr), "v"(v) : "memory");
                asm volatile("global_store_dword %0, %1, off sc0 sc1" :: "v"(addr), "v"(v) : "memory");
            }
            // prefetch x fragments for step s+1
            int xt = d ? (T_ - 2 - s) : (s + 1);
            const h8* xb = (const h8*)x16 + ((size_t)xt * 64 + grp * 8) * 64 + lane;
            #pragma unroll
            for (int kb = 0; kb < 8; ++kb) xf[kb] = xb[kb * 64];
        }
    }
    // final h (fp32)
    #pragma unroll
    for (int r = 0; r < 4; ++r)
        hfin[((size_t)d * B_ + grp * 16 + q * 4 + r) * H_ + p * 64 + w * 16 + l16] = hv4[r];
}

// ---------------------------------------------------------------------------
// K4: head. One block per batch row: a1 = relu([h_fwd|h_bwd] @ W1 + b1),
// logits = a1 @ W2 + b2, softmax over 32 classes. All fp32.
// ---------------------------------------------------------------------------
__global__ __launch_bounds__(256) void k_head(const float* __restrict__ hfin,
        const float* __restrict__ W1, const float* __restrict__ b1,
        const float* __restrict__ W2, const float* __restrict__ b2, float* __restrict__ out)
{
    const int b = blockIdx.x;
    const int tid = threadIdx.x;
    __shared__ float hcat[2 * H_];
    __shared__ float a1[256];
    if (tid < 128) {
        if (tid < 64)
            ((float4*)hcat)[tid] = ((const float4*)(hfin + (size_t)b * H_))[tid];
        else
            ((float4*)(hcat + H_))[tid - 64] = ((const float4*)(hfin + (size_t)(B_ + b) * H_))[tid - 64];
    }
    __syncthreads();
    {
        float s = b1[tid];
        #pragma unroll 4
        for (int k = 0; k < 2 * H_; ++k)
            s += hcat[k] * W1[(size_t)k * 256 + tid];
        a1[tid] = s > 0.f ? s : 0.f;
    }
    __syncthreads();
    if (tid < 32) {
        float s = b2[tid];
        #pragma unroll 4
        for (int j = 0; j < 256; ++j)
            s += a1[j] * W2[(size_t)j * 32 + tid];
        float mx = s;
        #pragma unroll
        for (int o = 16; o > 0; o >>= 1)
            mx = fmaxf(mx, __shfl_xor(mx, o, 32));
        float e = __expf(s - mx);
        float sum = e;
        #pragma unroll
        for (int o = 16; o > 0; o >>= 1)
            sum += __shfl_xor(sum, o, 32);
        out[(size_t)b * 32 + tid] = e / sum;
    }
}

// ---------------------------------------------------------------------------
extern "C" void kernel_launch(void* const* d_in, const int* in_sizes, int n_in,
                              void* d_out, int out_size, void* d_ws, size_t ws_size,
                              hipStream_t stream)
{
    (void)in_sizes; (void)n_in; (void)out_size; (void)ws_size;
    const int*   tok = (const int*)d_in[0];
    const float* emb = (const float*)d_in[1];
    const float* Wf  = (const float*)d_in[2];
    const float* Uf  = (const float*)d_in[3];
    const float* bf  = (const float*)d_in[4];
    const float* Wb  = (const float*)d_in[5];
    const float* Ub  = (const float*)d_in[6];
    const float* bb  = (const float*)d_in[7];
    const float* W1  = (const float*)d_in[8];
    const float* b1  = (const float*)d_in[9];
    const float* W2  = (const float*)d_in[10];
    const float* b2  = (const float*)d_in[11];
    float* out = (float*)d_out;

    char* ws = (char*)d_ws;
    _Float16* x16  = (_Float16*)(ws);                  // 33,554,432 B frag-ordered x
    _Float16* wp   = (_Float16*)(ws + 33554432);       //  2,097,152 B permuted W+U fp16
    unsigned* hx   = (unsigned*)(ws + 35651584);       //    524,288 B tagged h exchange
    float*    hfin = (float*)   (ws + 36175872);       //    262,144 B final h fp32
                                                       // total 36,438,016 B

    k_gather<<<T_, 256, 0, stream>>>(tok, emb, x16);
    k_perm  <<<64, 256, 0, stream>>>(Wf, Uf, Wb, Ub, wp);
    // clear exchange tags每 launch: a stale tag from the previous iteration is
    // bit-identical to the expected tag of the same step this iteration (latent
    // race on re-poisoned inputs). Stream-ordered, graph-capturable.
    hipMemsetAsync(hx, 0, 524288, stream);
    k_rnn   <<<64, 256, 0, stream>>>(x16, wp, bf, bb, hx, hfin);
    k_head  <<<B_, 256, 0, stream>>>(hfin, W1, b1, W2, b2, out);
}

// Round 2
// 2379.190 us; speedup vs baseline: 1.3808x; 1.3808x over previous
//
#include <hip/hip_runtime.h>
#include <hip/hip_bf16.h>
#include <hip/hip_fp16.h>

#define T_ 512
#define B_ 128
#define E_ 256
#define H_ 256
#define NPROD 240
#define AHEAD 28

typedef _Float16 h8 __attribute__((ext_vector_type(8)));
typedef float    f4 __attribute__((ext_vector_type(4)));
typedef unsigned u4 __attribute__((ext_vector_type(4)));
typedef unsigned u2 __attribute__((ext_vector_type(2)));
typedef int      i4 __attribute__((ext_vector_type(4)));

// ---------------------------------------------------------------------------
// workspace layout (bytes)                         size
//   wp   (fp16 W/U B-frags, k_perm)            0   2,097,152
//   uq   (i8 U frags, k_permU)         2,097,152     524,288
//   scl  (f32 dequant scales)          2,621,440       8,192
//   ring (fp16 xW+b, 32 slots)         4,194,304  16,777,216
//   flags(u32 [slot][d])              20,971,520         256
//   prog (u32 [16])                   20,971,776         256  (pad)
//   hfin (f32 final h)                20,972,032     262,144
// ---------------------------------------------------------------------------

// ---------------------------------------------------------------------------
// K2: weight permute+convert to fp16 B-fragment layout (unchanged).
// wp element [(d*32 + mat*16 + p*4 + w)*16384 + nt*4096 + n*256 + k] =
//   M[k][nt*256 + p*64 + w*16 + n]. Producers use mat=0 (W) blocks.
// ---------------------------------------------------------------------------
__global__ __launch_bounds__(256) void k_perm(const float* __restrict__ Wf, const float* __restrict__ Uf,
        const float* __restrict__ Wb, const float* __restrict__ Ub, _Float16* __restrict__ wp)
{
    const int bid = blockIdx.x;
    const int d = bid >> 5, mat = (bid >> 4) & 1, p = (bid >> 2) & 3, w = bid & 3;
    const float* src = d ? (mat ? Ub : Wb) : (mat ? Uf : Wf);
    _Float16* dst = wp + (size_t)bid * 16384;
    const int tid = threadIdx.x;
    const int cbase = p * 64 + w * 16;
    __shared__ float S[256][17];
    for (int nt = 0; nt < 4; ++nt) {
        for (int it = 0; it < 16; ++it) {
            int idx = it * 256 + tid;
            int k = idx >> 4, c16 = idx & 15;
            S[k][c16] = src[(size_t)k * 1024 + nt * 256 + cbase + c16];
        }
        __syncthreads();
        for (int it = 0; it < 16; ++it) {
            int idx = it * 256 + tid;
            int k = idx & 255, c16 = idx >> 8;
            dst[(size_t)nt * 4096 + c16 * 256 + k] = (_Float16)S[k][c16];
        }
        __syncthreads();
    }
}

// ---------------------------------------------------------------------------
// K2b: per-column int8 quantization of U into i8 B-fragment layout.
// Consumer col map: col = g*256 + cg*64 + sub*16 + n, nt' = g*4+sub (0..15).
// Frag byte [bid*65536 + ((nt'*4+kb)*64 + qq*16 + n)*16 + j] = Uq[k][col],
//   k = kb*64 + qq*16 + j.  scl[bid*256 + nt'*16 + n] = absmax/(127*127).
// ---------------------------------------------------------------------------
__global__ __launch_bounds__(256) void k_permU(const float* __restrict__ Uf,
        const float* __restrict__ Ub, char* __restrict__ uq, float* __restrict__ scl)
{
    const int bid = blockIdx.x;          // d*4 + cg
    const int d = bid >> 2, cg = bid & 3;
    const float* U = d ? Ub : Uf;
    const int tid = threadIdx.x;         // nt'*16 + n
    const int nt = tid >> 4, n = tid & 15;
    const int g = nt >> 2, sub = nt & 3;
    const int col = g * 256 + cg * 64 + sub * 16 + n;
    float mx = 0.f;
    for (int k = 0; k < H_; ++k)
        mx = fmaxf(mx, fabsf(U[(size_t)k * 1024 + col]));
    float su = mx > 0.f ? mx * (1.f / 127.f) : 1.f;
    scl[bid * 256 + tid] = su * (1.f / 127.f);
    float inv = 1.f / su;
    char* dst = uq + (size_t)bid * 65536;
    for (int k = 0; k < H_; ++k) {
        float v = U[(size_t)k * 1024 + col] * inv;
        int qv = (int)__builtin_rintf(v);
        qv = qv > 127 ? 127 : (qv < -127 ? -127 : qv);
        int kb = k >> 6, qq = (k >> 4) & 3, j = k & 15;
        dst[(size_t)((nt * 4 + kb) * 64 + qq * 16 + n) * 16 + j] = (char)qv;
    }
}

__device__ __forceinline__ float fsig(float x) {
    float t = __expf(-fabsf(x));
    float r = __builtin_amdgcn_rcpf(1.0f + t);
    return x >= 0.f ? r : 1.0f - r;
}
__device__ __forceinline__ float ftanh(float x) {
    float t = __expf(-2.0f * fabsf(x));
    float r = (1.0f - t) * __builtin_amdgcn_rcpf(1.0f + t);
    return x >= 0.f ? r : -r;
}

// ---------------------------------------------------------------------------
// K3: fused producer/consumer kernel, 256 WGs x 256 threads.
//  bid 0..15   : consumers, one per (d, grp of 16 batch rows). 4 waves, each
//                holds a 256-col i8 slice of U (128 VGPRs). h-exchange is
//                pure LDS (double-buffered, XOR-tile swizzle), ONE barrier
//                per step. xW comes from the ring, prefetched 1 step ahead.
//  bid 16..255 : producers. Tiles tau = s*2+d round-robin; per tile: gather
//                emb rows for t (=s fwd, T-1-s bwd), x@W+b via fp16 MFMA,
//                store fp16 to ring slot s&31, then set flag[s&31][d]=s+1.
//                Throttled to stay < AHEAD slots ahead of min consumer.
// ---------------------------------------------------------------------------
__global__ __launch_bounds__(256, 1) void k_fused(
        const int* __restrict__ tok, const float* __restrict__ emb,
        const _Float16* __restrict__ wp, const char* __restrict__ uq,
        const float* __restrict__ scl, const float* __restrict__ bf,
        const float* __restrict__ bb, _Float16* __restrict__ ring,
        unsigned* __restrict__ flags, unsigned* __restrict__ prog,
        float* __restrict__ hfin)
{
    const int bid = blockIdx.x;
    const int tid = threadIdx.x;
    const int w = tid >> 6, lane = tid & 63;
    const int l16 = lane & 15, q = lane >> 4;

    __shared__ int rows[B_];
    __shared__ h8 xle[64 * 64];        // 64 KB producer x-fragment staging
    __shared__ char hbuf[2][4096];     // consumer h exchange (i8, swizzled)

    if (bid < 16) {
        // ================= consumer =================
        const int d = bid >> 3, grp = bid & 7;
        const int cg = w;
        // U i8 weights: 64 x i4 = 128 VGPRs... per [nt'][kb]
        i4 uw[16][4];
        {
            const char* ub = uq + (size_t)(d * 4 + cg) * 65536;
            #pragma unroll
            for (int nt = 0; nt < 16; ++nt)
                #pragma unroll
                for (int kb = 0; kb < 4; ++kb)
                    uw[nt][kb] = *(const i4*)(ub + (size_t)((nt * 4 + kb) * 64 + lane) * 16);
            #pragma unroll
            for (int nt = 0; nt < 16; ++nt)
                #pragma unroll
                for (int kb = 0; kb < 4; ++kb)
                    asm volatile("" : "+v"(uw[nt][kb]));
        }
        float sclv[16];
        #pragma unroll
        for (int nt = 0; nt < 16; ++nt)
            sclv[nt] = scl[(d * 4 + cg) * 256 + nt * 16 + l16];

        float c_[4][4], h_[4][4];
        #pragma unroll
        for (int a = 0; a < 4; ++a)
            #pragma unroll
            for (int b = 0; b < 4; ++b) { c_[a][b] = 0.f; h_[a][b] = 0.f; }

        u4 xw[8];
        unsigned fnext = 0;
#define XLD(i, OFF, P) asm volatile("global_load_dwordx4 %0, %1, off offset:" OFF " sc0 sc1" : "=v"(xw[i]) : "v"(P) : "memory")
        // prologue: blocking wait for slot 0, issue xw(0) + flag(1) prefetch
        {
            const unsigned* f0 = flags + d;   // slot 0
            unsigned fv;
            while (true) {
                asm volatile("global_load_dword %0, %1, off sc0 sc1" : "=v"(fv) : "v"(f0) : "memory");
                asm volatile("s_waitcnt vmcnt(0)" : "+v"(fv) :: "memory");
                if (fv == 1u) break;
                __builtin_amdgcn_s_sleep(8);
            }
            const _Float16* xp = ring + ((size_t)(0 * 2 + d) * 8 + grp) * 4096 * 4
                                      + (size_t)cg * 4096 + lane * 64;
            XLD(0, "0", xp); XLD(1, "16", xp); XLD(2, "32", xp); XLD(3, "48", xp);
            XLD(4, "64", xp); XLD(5, "80", xp); XLD(6, "96", xp); XLD(7, "112", xp);
            const unsigned* f1 = flags + 2 + d;
            asm volatile("global_load_dword %0, %1, off sc0 sc1" : "=v"(fnext) : "v"(f1) : "memory");
        }

        for (int s = 0; s < T_; ++s) {
            if (tid == 0) {
                unsigned pv = (unsigned)s;
                asm volatile("global_store_dword %0, %1, off sc0 sc1" :: "v"(prog + bid), "v"(pv) : "memory");
            }
            // ---- h @ U (i8 MFMA) ----
            i4 acc[16];
            {
                i4 z = {0, 0, 0, 0};
                #pragma unroll
                for (int nt = 0; nt < 16; ++nt) acc[nt] = z;
            }
            if (s > 0) {
                const char* hb = hbuf[(s - 1) & 1];
                i4 hf[4];
                #pragma unroll
                for (int kb = 0; kb < 4; ++kb)
                    hf[kb] = *(const i4*)(hb + l16 * 256 + (((kb * 4 + q) ^ l16) << 4));
                #pragma unroll
                for (int kb = 0; kb < 4; ++kb)
                    #pragma unroll
                    for (int nt = 0; nt < 16; ++nt)
                        acc[nt] = __builtin_amdgcn_mfma_i32_16x16x64_i8(hf[kb], uw[nt][kb], acc[nt], 0, 0, 0);
            }
            // xw(s) + fnext arrived long ago (issued prev step): drain
            asm volatile("s_waitcnt vmcnt(0)"
                : "+v"(xw[0]), "+v"(xw[1]), "+v"(xw[2]), "+v"(xw[3]),
                  "+v"(xw[4]), "+v"(xw[5]), "+v"(xw[6]), "+v"(xw[7]), "+v"(fnext)
                :: "memory");
            h8 xh[8];
            #pragma unroll
            for (int j = 0; j < 8; ++j) xh[j] = __builtin_bit_cast(h8, xw[j]);

            // ---- dequant + gates + h publish ----
            char* hb1 = hbuf[s & 1];
#define ZG(gg) ((float)acc[(gg) * 4 + sub][r] * sclv[(gg) * 4 + sub] \
              + (float)xh[((gg) * 4 + sub) >> 1][(((gg) * 4 + sub) & 1) * 4 + r])
            #pragma unroll
            for (int sub = 0; sub < 4; ++sub)
                #pragma unroll
                for (int r = 0; r < 4; ++r) {
                    float zi = ZG(0), zf = ZG(1), zg = ZG(2), zo = ZG(3);
                    float cn = fsig(zf) * c_[sub][r] + fsig(zi) * ftanh(zg);
                    c_[sub][r] = cn;
                    float hh = fsig(zo) * ftanh(cn);
                    h_[sub][r] = hh;
                    int hq = (int)__builtin_rintf(hh * 127.f);
                    int row = q * 4 + r;
                    hb1[row * 256 + (((cg * 4 + sub) ^ row) << 4) + l16] = (char)hq;
                }
#undef ZG
            // ---- prefetch next step's xw/flag (off-chain) ----
            if (s + 1 < T_) {
                if (fnext != (unsigned)(s + 2)) {
                    const unsigned* fp1 = flags + ((s + 1) & 31) * 2 + d;
                    unsigned fv;
                    while (true) {
                        asm volatile("global_load_dword %0, %1, off sc0 sc1" : "=v"(fv) : "v"(fp1) : "memory");
                        asm volatile("s_waitcnt vmcnt(0)" : "+v"(fv) :: "memory");
                        if (fv == (unsigned)(s + 2)) break;
                        __builtin_amdgcn_s_sleep(8);
                    }
                }
                const _Float16* xp = ring + ((size_t)(((s + 1) & 31) * 2 + d) * 8 + grp) * 4096 * 4
                                          + (size_t)cg * 4096 + lane * 64;
                XLD(0, "0", xp); XLD(1, "16", xp); XLD(2, "32", xp); XLD(3, "48", xp);
                XLD(4, "64", xp); XLD(5, "80", xp); XLD(6, "96", xp); XLD(7, "112", xp);
                if (s + 2 < T_) {
                    const unsigned* f2 = flags + ((s + 2) & 31) * 2 + d;
                    asm volatile("global_load_dword %0, %1, off sc0 sc1" : "=v"(fnext) : "v"(f2) : "memory");
                }
            }
            __syncthreads();
        }
        // final h (fp32)
        #pragma unroll
        for (int sub = 0; sub < 4; ++sub)
            #pragma unroll
            for (int r = 0; r < 4; ++r)
                hfin[((size_t)d * B_ + grp * 16 + q * 4 + r) * H_ + cg * 64 + sub * 16 + l16] = h_[sub][r];
#undef XLD
    } else {
        // ================= producer =================
        const int pid = bid - 16;
        const float* biasf = bf;
        const float* biasb = bb;
        for (int tile = pid; tile < 2 * T_; tile += NPROD) {
            const int s = tile >> 1, d = tile & 1;
            // throttle: stay < AHEAD ahead of slowest consumer
            if (tid == 0) {
                while (true) {
                    unsigned mn = 0xffffffffu;
                    for (int i = 0; i < 16; ++i) {
                        unsigned v;
                        asm volatile("global_load_dword %0, %1, off sc0 sc1" : "=v"(v) : "v"(prog + i) : "memory");
                        asm volatile("s_waitcnt vmcnt(0)" : "+v"(v) :: "memory");
                        if (v < mn) mn = v;
                    }
                    if ((unsigned)s < mn + AHEAD) break;
                    __builtin_amdgcn_s_sleep(32);
                }
            }
            __syncthreads();
            const int t = d ? (T_ - 1 - s) : s;
            if (tid < B_) rows[tid] = tok[(size_t)tid * T_ + t];
            __syncthreads();
            // gather x fragments -> LDS (A-frag order, same as proven k_gather)
            for (int it = 0; it < 16; ++it) {
                int pair = it * 4 + w;           // pair = grp*8 + kb
                int g8 = pair >> 3, kb = pair & 7;
                int b = g8 * 16 + l16;
                int e = kb * 32 + q * 8;
                const float* src = emb + (size_t)rows[b] * E_ + e;
                float4 a = *(const float4*)src;
                float4 c = *(const float4*)(src + 4);
                h8 hv;
                hv[0] = (_Float16)a.x; hv[1] = (_Float16)a.y; hv[2] = (_Float16)a.z; hv[3] = (_Float16)a.w;
                hv[4] = (_Float16)c.x; hv[5] = (_Float16)c.y; hv[6] = (_Float16)c.z; hv[7] = (_Float16)c.w;
                xle[pair * 64 + lane] = hv;
            }
            __syncthreads();
            const float* bias = d ? biasb : biasf;
            for (int p = 0; p < 4; ++p) {
                const _Float16* bx = wp + (size_t)(d * 32 + p * 4 + w) * 16384;
                h8 wb[4][8];
                #pragma unroll
                for (int nt = 0; nt < 4; ++nt)
                    #pragma unroll
                    for (int kb = 0; kb < 8; ++kb)
                        wb[nt][kb] = *(const h8*)(bx + nt * 4096 + l16 * 256 + kb * 32 + q * 8);
                float bvv[4];
                #pragma unroll
                for (int nt = 0; nt < 4; ++nt)
                    bvv[nt] = bias[nt * 256 + p * 64 + w * 16 + l16];
                for (int g8 = 0; g8 < 8; ++g8) {
                    h8 xa[8];
                    #pragma unroll
                    for (int kb = 0; kb < 8; ++kb)
                        xa[kb] = xle[(g8 * 8 + kb) * 64 + lane];
                    f4 acc[4];
                    #pragma unroll
                    for (int nt = 0; nt < 4; ++nt)
                        acc[nt] = (f4){bvv[nt], bvv[nt], bvv[nt], bvv[nt]};
                    #pragma unroll
                    for (int kb = 0; kb < 8; ++kb)
                        #pragma unroll
                        for (int nt = 0; nt < 4; ++nt)
                            acc[nt] = __builtin_amdgcn_mfma_f32_16x16x32_f16(xa[kb], wb[nt][kb], acc[nt], 0, 0, 0);
                    _Float16* dst = ring + ((size_t)((s & 31) * 2 + d) * 8 + g8) * 4096 * 4
                                         + (size_t)p * 4096 + lane * 64;
                    #pragma unroll
                    for (int nt = 0; nt < 4; ++nt) {
                        _Float16 e0 = (_Float16)acc[nt][0], e1 = (_Float16)acc[nt][1];
                        _Float16 e2 = (_Float16)acc[nt][2], e3 = (_Float16)acc[nt][3];
                        unsigned lo = (unsigned)__builtin_bit_cast(unsigned short, e0)
                                    | ((unsigned)__builtin_bit_cast(unsigned short, e1) << 16);
                        unsigned hi = (unsigned)__builtin_bit_cast(unsigned short, e2)
                                    | ((unsigned)__builtin_bit_cast(unsigned short, e3) << 16);
                        u2 val = {lo, hi};
                        _Float16* da = dst + (nt * 4 + w) * 4;
                        asm volatile("global_store_dwordx2 %0, %1, off sc0 sc1" :: "v"(da), "v"(val) : "memory");
                    }
                }
            }
            asm volatile("s_waitcnt vmcnt(0)" ::: "memory");
            __syncthreads();   // all 4 waves' ring stores complete
            if (tid == 0) {
                unsigned fvv = (unsigned)(s + 1);
                asm volatile("global_store_dword %0, %1, off sc0 sc1" :: "v"(flags + (s & 31) * 2 + d), "v"(fvv) : "memory");
            }
        }
    }
}

// ---------------------------------------------------------------------------
// K4: head (unchanged).
// ---------------------------------------------------------------------------
__global__ __launch_bounds__(256) void k_head(const float* __restrict__ hfin,
        const float* __restrict__ W1, const float* __restrict__ b1,
        const float* __restrict__ W2, const float* __restrict__ b2, float* __restrict__ out)
{
    const int b = blockIdx.x;
    const int tid = threadIdx.x;
    __shared__ float hcat[2 * H_];
    __shared__ float a1[256];
    if (tid < 128) {
        if (tid < 64)
            ((float4*)hcat)[tid] = ((const float4*)(hfin + (size_t)b * H_))[tid];
        else
            ((float4*)(hcat + H_))[tid - 64] = ((const float4*)(hfin + (size_t)(B_ + b) * H_))[tid - 64];
    }
    __syncthreads();
    {
        float s = b1[tid];
        #pragma unroll 4
        for (int k = 0; k < 2 * H_; ++k)
            s += hcat[k] * W1[(size_t)k * 256 + tid];
        a1[tid] = s > 0.f ? s : 0.f;
    }
    __syncthreads();
    if (tid < 32) {
        float s = b2[tid];
        #pragma unroll 4
        for (int j = 0; j < 256; ++j)
            s += a1[j] * W2[(size_t)j * 32 + tid];
        float mx = s;
        #pragma unroll
        for (int o = 16; o > 0; o >>= 1)
            mx = fmaxf(mx, __shfl_xor(mx, o, 32));
        float e = __expf(s - mx);
        float sum = e;
        #pragma unroll
        for (int o = 16; o > 0; o >>= 1)
            sum += __shfl_xor(sum, o, 32);
        out[(size_t)b * 32 + tid] = e / sum;
    }
}

// ---------------------------------------------------------------------------
extern "C" void kernel_launch(void* const* d_in, const int* in_sizes, int n_in,
                              void* d_out, int out_size, void* d_ws, size_t ws_size,
                              hipStream_t stream)
{
    (void)in_sizes; (void)n_in; (void)out_size; (void)ws_size;
    const int*   tok = (const int*)d_in[0];
    const float* emb = (const float*)d_in[1];
    const float* Wf  = (const float*)d_in[2];
    const float* Uf  = (const float*)d_in[3];
    const float* bf  = (const float*)d_in[4];
    const float* Wb  = (const float*)d_in[5];
    const float* Ub  = (const float*)d_in[6];
    const float* bb  = (const float*)d_in[7];
    const float* W1  = (const float*)d_in[8];
    const float* b1  = (const float*)d_in[9];
    const float* W2  = (const float*)d_in[10];
    const float* b2  = (const float*)d_in[11];
    float* out = (float*)d_out;

    char* ws = (char*)d_ws;
    _Float16* wp    = (_Float16*)(ws);               //  2,097,152 B fp16 W/U frags
    char*     uq    = (char*)    (ws + 2097152);     //    524,288 B i8 U frags
    float*    scl   = (float*)   (ws + 2621440);     //      8,192 B dequant scales
    _Float16* ring  = (_Float16*)(ws + 4194304);     // 16,777,216 B xW ring (32 slots)
    unsigned* flags = (unsigned*)(ws + 20971520);    //        256 B slot flags
    unsigned* prog  = (unsigned*)(ws + 20971776);    //        256 B consumer progress
    float*    hfin  = (float*)   (ws + 20972032);    //    262,144 B final h fp32

    k_perm <<<64, 256, 0, stream>>>(Wf, Uf, Wb, Ub, wp);
    k_permU<<<8, 256, 0, stream>>>(Uf, Ub, uq, scl);
    // flags/progress must be zeroed every launch: stale tags from a previous
    // iteration are bit-identical to this iteration's expected tags.
    hipMemsetAsync(flags, 0, 512, stream);
    k_fused<<<256, 256, 0, stream>>>(tok, emb, wp, uq, scl, bf, bb, ring, flags, prog, hfin);
    k_head <<<B_, 256, 0, stream>>>(hfin, W1, b1, W2, b2, out);
}

// Round 3
// 2073.172 us; speedup vs baseline: 1.5847x; 1.1476x over previous
//
#include <hip/hip_runtime.h>
#include <hip/hip_fp16.h>

#define T_ 512
#define B_ 128
#define E_ 256
#define H_ 256

typedef _Float16 h8 __attribute__((ext_vector_type(8)));
typedef _Float16 h4 __attribute__((ext_vector_type(4)));
typedef float    f4 __attribute__((ext_vector_type(4)));
typedef unsigned u4 __attribute__((ext_vector_type(4)));
typedef int      i4 __attribute__((ext_vector_type(4)));

// ---------------------------------------------------------------------------
// workspace layout (bytes)
//   wp    (fp16 W frags, k_perm)            0   2,097,152
//   uq    (i8 U frags, k_permU)     2,097,152     524,288
//   scl   (f32 dequant scales)      2,621,440       8,192
//   hstate(f32 c/h chunk state)     2,629,632     524,288
//   hfin  (f32 final h)             3,153,920     262,144
//   xwbuf (fp16 z_x, chunked)       4,194,304   chunkT*524,288
// ---------------------------------------------------------------------------

// ---------------------------------------------------------------------------
// K2: weight permute+convert to fp16 B-fragment layout (proven, unchanged).
// wp element [(d*32 + mat*16 + p*4 + w)*16384 + nt*4096 + n*256 + k] =
//   M[k][nt*256 + p*64 + w*16 + n]. k_xw uses mat=0 (W) blocks only.
// ---------------------------------------------------------------------------
__global__ __launch_bounds__(256) void k_perm(const float* __restrict__ Wf, const float* __restrict__ Uf,
        const float* __restrict__ Wb, const float* __restrict__ Ub, _Float16* __restrict__ wp)
{
    const int bid = blockIdx.x;
    const int d = bid >> 5, mat = (bid >> 4) & 1, p = (bid >> 2) & 3, w = bid & 3;
    const float* src = d ? (mat ? Ub : Wb) : (mat ? Uf : Wf);
    _Float16* dst = wp + (size_t)bid * 16384;
    const int tid = threadIdx.x;
    const int cbase = p * 64 + w * 16;
    __shared__ float S[256][17];
    for (int nt = 0; nt < 4; ++nt) {
        for (int it = 0; it < 16; ++it) {
            int idx = it * 256 + tid;
            int k = idx >> 4, c16 = idx & 15;
            S[k][c16] = src[(size_t)k * 1024 + nt * 256 + cbase + c16];
        }
        __syncthreads();
        for (int it = 0; it < 16; ++it) {
            int idx = it * 256 + tid;
            int k = idx & 255, c16 = idx >> 8;
            dst[(size_t)nt * 4096 + c16 * 256 + k] = (_Float16)S[k][c16];
        }
        __syncthreads();
    }
}

// ---------------------------------------------------------------------------
// K2b: per-column int8 quantization of U into i8 B-fragments for the 8-wave
// consumer. Block bid = d*8+cw handles cols {g*256 + cw*32 + sub*16 + n}.
// dst byte [bid*32768 + ((nt*4+kb)*64 + q*16 + n)*16 + j] = Uq[kb*64+q*16+j][col],
// nt = g*2+sub. scl[bid*128 + nt*16 + n] = absmax/(127*127).
// ---------------------------------------------------------------------------
__global__ __launch_bounds__(256) void k_permU(const float* __restrict__ Uf,
        const float* __restrict__ Ub, char* __restrict__ uq, float* __restrict__ scl)
{
    const int bid = blockIdx.x;          // d*8 + cw
    const int d = bid >> 3, cw = bid & 7;
    const float* U = d ? Ub : Uf;
    const int tid = threadIdx.x;
    if (tid >= 128) return;
    const int nt = tid >> 4, n = tid & 15;
    const int g = nt >> 1, sub = nt & 1;
    const int col = g * 256 + cw * 32 + sub * 16 + n;
    float mx = 0.f;
    for (int k = 0; k < H_; ++k)
        mx = fmaxf(mx, fabsf(U[(size_t)k * 1024 + col]));
    float su = mx > 0.f ? mx * (1.f / 127.f) : 1.f;
    scl[bid * 128 + tid] = su * (1.f / 127.f);
    float inv = 1.f / su;
    char* dst = uq + (size_t)bid * 32768;
    for (int k = 0; k < H_; ++k) {
        float v = U[(size_t)k * 1024 + col] * inv;
        int qv = (int)__builtin_rintf(v);
        qv = qv > 127 ? 127 : (qv < -127 ? -127 : qv);
        dst[(size_t)((nt * 4 + (k >> 6)) * 64 + ((k >> 4) & 3) * 16 + n) * 16 + (k & 15)] = (char)qv;
    }
}

// ---------------------------------------------------------------------------
// K3a: z_x = x@W + b GEMM (throughput, all CUs). One block per (s_local, d).
// Output layout = consumer fragment order:
//   half [((sl*2+d)*8 + g8)*16384 + cw*2048 + lane*32 + nt''*4 + r] =
//     z[row = g8*16 + (lane>>4)*4 + r][col = g*256 + cw*32 + sub*16 + (lane&15)]
//   with nt'' = g*2+sub. Producer map: cw = p*2+(w>>1), nt'' = nt*2+(w&1).
// ---------------------------------------------------------------------------
__global__ __launch_bounds__(256) void k_xw(const int* __restrict__ tok,
        const float* __restrict__ emb, const _Float16* __restrict__ wp,
        const float* __restrict__ bf, const float* __restrict__ bb,
        _Float16* __restrict__ xwbuf, int s0)
{
    const int bid = blockIdx.x;
    const int sl = bid >> 1, d = bid & 1;
    const int s = s0 + sl;
    const int tid = threadIdx.x;
    const int w = tid >> 6, lane = tid & 63;
    const int l16 = lane & 15, q = lane >> 4;
    __shared__ int rows[B_];
    __shared__ h8 xle[64 * 64];
    const int t = d ? (T_ - 1 - s) : s;
    if (tid < B_) rows[tid] = tok[(size_t)tid * T_ + t];
    __syncthreads();
    for (int it = 0; it < 16; ++it) {
        int pair = it * 4 + w;           // pair = g8*8 + kb
        int g8 = pair >> 3, kb = pair & 7;
        int b = g8 * 16 + l16;
        int e = kb * 32 + q * 8;
        const float* src = emb + (size_t)rows[b] * E_ + e;
        float4 a = *(const float4*)src;
        float4 c = *(const float4*)(src + 4);
        h8 hv;
        hv[0] = (_Float16)a.x; hv[1] = (_Float16)a.y; hv[2] = (_Float16)a.z; hv[3] = (_Float16)a.w;
        hv[4] = (_Float16)c.x; hv[5] = (_Float16)c.y; hv[6] = (_Float16)c.z; hv[7] = (_Float16)c.w;
        xle[pair * 64 + lane] = hv;
    }
    __syncthreads();
    const float* bias = d ? bb : bf;
    for (int p = 0; p < 4; ++p) {
        const _Float16* bx = wp + (size_t)(d * 32 + p * 4 + w) * 16384;
        h8 wb[4][8];
        #pragma unroll
        for (int nt = 0; nt < 4; ++nt)
            #pragma unroll
            for (int kb = 0; kb < 8; ++kb)
                wb[nt][kb] = *(const h8*)(bx + nt * 4096 + l16 * 256 + kb * 32 + q * 8);
        float bvv[4];
        #pragma unroll
        for (int nt = 0; nt < 4; ++nt)
            bvv[nt] = bias[nt * 256 + p * 64 + w * 16 + l16];
        for (int g8 = 0; g8 < 8; ++g8) {
            h8 xa[8];
            #pragma unroll
            for (int kb = 0; kb < 8; ++kb)
                xa[kb] = xle[(g8 * 8 + kb) * 64 + lane];
            f4 acc[4];
            #pragma unroll
            for (int nt = 0; nt < 4; ++nt)
                acc[nt] = (f4){bvv[nt], bvv[nt], bvv[nt], bvv[nt]};
            #pragma unroll
            for (int kb = 0; kb < 8; ++kb)
                #pragma unroll
                for (int nt = 0; nt < 4; ++nt)
                    acc[nt] = __builtin_amdgcn_mfma_f32_16x16x32_f16(xa[kb], wb[nt][kb], acc[nt], 0, 0, 0);
            _Float16* dst = xwbuf + (((size_t)sl * 2 + d) * 8 + g8) * 16384
                          + (size_t)(p * 2 + (w >> 1)) * 2048 + (size_t)lane * 32 + (w & 1) * 4;
            #pragma unroll
            for (int nt = 0; nt < 4; ++nt) {
                h4 v = { (_Float16)acc[nt][0], (_Float16)acc[nt][1],
                         (_Float16)acc[nt][2], (_Float16)acc[nt][3] };
                *(h4*)(dst + nt * 8) = v;
            }
        }
    }
}

// ---------------------------------------------------------------------------
// K3b: recurrence. 16 WGs (d*8+grp) x 512 threads (8 waves). Wave cw owns
// h-units [cw*32, cw*32+32) for all 4 gates: U int8 in 128 VGPRs. NOTHING
// global in the loop except the prefetched xw stream (plain cached loads,
// 2 steps ahead, counted vmcnt(4) — never 0 mid-loop). h exchange is pure
// LDS (8KB double buffer, XOR-chunk swizzle), ONE barrier per step.
// ---------------------------------------------------------------------------
__device__ __forceinline__ float fsig(float x) {
    float t = __expf(-fabsf(x));
    float r = __builtin_amdgcn_rcpf(1.0f + t);
    return x >= 0.f ? r : 1.0f - r;
}
__device__ __forceinline__ float ftanh(float x) {
    float t = __expf(-2.0f * fabsf(x));
    float r = (1.0f - t) * __builtin_amdgcn_rcpf(1.0f + t);
    return x >= 0.f ? r : -r;
}

#define XLD(D, P, OFF) asm volatile("global_load_dwordx4 %0, %1, off offset:" OFF \
    : "=v"(D) : "v"(P) : "memory")

__global__ __launch_bounds__(512, 2) void k_rnn(
        const _Float16* __restrict__ xwbuf, const char* __restrict__ uq,
        const float* __restrict__ scl, float* __restrict__ hstate,
        float* __restrict__ hfin, int s0, int nsteps)
{
    const int bid = blockIdx.x;          // d*8 + grp
    const int d = bid >> 3, grp = bid & 7;
    const int tid = threadIdx.x;
    const int cw = tid >> 6, lane = tid & 63;
    const int l16 = lane & 15, q = lane >> 4;

    __shared__ char hbuf[2][4096];       // [parity][row 16][unit-chunk^row 16][16B]

    // U i8: uw[nt''][kb], nt''=g*2+sub (8), kb k-quarter (4) -> 128 VGPRs
    i4 uw[8][4];
    {
        const char* ub = uq + (size_t)(d * 8 + cw) * 32768;
        #pragma unroll
        for (int nt = 0; nt < 8; ++nt)
            #pragma unroll
            for (int kb = 0; kb < 4; ++kb)
                uw[nt][kb] = *(const i4*)(ub + (size_t)((nt * 4 + kb) * 64 + lane) * 16);
        #pragma unroll
        for (int nt = 0; nt < 8; ++nt)
            #pragma unroll
            for (int kb = 0; kb < 4; ++kb)
                asm volatile("" : "+v"(uw[nt][kb]));
    }
    float sclv[8];
    #pragma unroll
    for (int nt = 0; nt < 8; ++nt)
        sclv[nt] = scl[(d * 8 + cw) * 128 + nt * 16 + l16];

    float c8[8], hh8[8];
    if (s0 == 0) {
        #pragma unroll
        for (int j = 0; j < 8; ++j) { c8[j] = 0.f; hh8[j] = 0.f; }
    } else {
        const float* st = hstate + ((size_t)(bid * 8 + cw) * 64 + lane) * 16;
        #pragma unroll
        for (int j = 0; j < 8; ++j) { c8[j] = st[j]; hh8[j] = st[8 + j]; }
        char* hb = hbuf[(s0 - 1) & 1];   // rebuild h_{s0-1} exchange tile
        #pragma unroll
        for (int sub = 0; sub < 2; ++sub)
            #pragma unroll
            for (int r = 0; r < 4; ++r) {
                int j = sub * 4 + r;
                int hq = (int)__builtin_rintf(hh8[j] * 127.f);
                int row = q * 4 + r;
                hb[row * 256 + (((cw * 2 + sub) ^ row) << 4) + l16] = (char)hq;
            }
    }
    __syncthreads();

    const _Float16* xbase = xwbuf + ((size_t)d * 8 + grp) * 16384
                          + (size_t)cw * 2048 + (size_t)lane * 32;
    u4 xwA[4], xwB[4];
    {
        const _Float16* pp = xbase;
        XLD(xwA[0], pp, "0"); XLD(xwA[1], pp, "16"); XLD(xwA[2], pp, "32"); XLD(xwA[3], pp, "48");
        const _Float16* p2 = xbase + 262144;
        XLD(xwB[0], p2, "0"); XLD(xwB[1], p2, "16"); XLD(xwB[2], p2, "32"); XLD(xwB[3], p2, "48");
    }

#define STEP(XW, I, VM)                                                          \
    {                                                                            \
        const int s_ = s0 + (I);                                                 \
        i4 acc[8];                                                               \
        _Pragma("unroll")                                                        \
        for (int nt = 0; nt < 8; ++nt) acc[nt] = (i4){0, 0, 0, 0};               \
        if (s_ > 0) {                                                            \
            const char* hb = hbuf[(s_ - 1) & 1];                                 \
            i4 hf[4];                                                            \
            _Pragma("unroll")                                                    \
            for (int kb = 0; kb < 4; ++kb)                                       \
                hf[kb] = *(const i4*)(hb + l16 * 256 + (((kb * 4 + q) ^ l16) << 4)); \
            _Pragma("unroll")                                                    \
            for (int kb = 0; kb < 4; ++kb)                                       \
                _Pragma("unroll")                                                \
                for (int nt = 0; nt < 8; ++nt)                                   \
                    acc[nt] = __builtin_amdgcn_mfma_i32_16x16x64_i8(hf[kb], uw[nt][kb], acc[nt], 0, 0, 0); \
        }                                                                        \
        asm volatile("s_waitcnt " VM                                             \
            : "+v"(XW[0]), "+v"(XW[1]), "+v"(XW[2]), "+v"(XW[3]) :: "memory");   \
        h8 xh[4];                                                                \
        _Pragma("unroll")                                                        \
        for (int jj = 0; jj < 4; ++jj) xh[jj] = __builtin_bit_cast(h8, XW[jj]);  \
        if ((I) + 2 < nsteps) {                                                  \
            const _Float16* pp = xbase + (size_t)((I) + 2) * 262144;             \
            XLD(XW[0], pp, "0"); XLD(XW[1], pp, "16");                           \
            XLD(XW[2], pp, "32"); XLD(XW[3], pp, "48");                          \
        }                                                                        \
        char* hbw = hbuf[s_ & 1];                                                \
        _Pragma("unroll")                                                        \
        for (int sub = 0; sub < 2; ++sub)                                        \
            _Pragma("unroll")                                                    \
            for (int r = 0; r < 4; ++r) {                                        \
                const int j = sub * 4 + r;                                       \
                float zi = (float)acc[sub][r]     * sclv[sub]     + (float)xh[0][j]; \
                float zf = (float)acc[2 + sub][r] * sclv[2 + sub] + (float)xh[1][j]; \
                float zg = (float)acc[4 + sub][r] * sclv[4 + sub] + (float)xh[2][j]; \
                float zo = (float)acc[6 + sub][r] * sclv[6 + sub] + (float)xh[3][j]; \
                float cn = fsig(zf) * c8[j] + fsig(zi) * ftanh(zg);              \
                c8[j] = cn;                                                      \
                float hv = fsig(zo) * ftanh(cn);                                 \
                hh8[j] = hv;                                                     \
                int hq = (int)__builtin_rintf(hv * 127.f);                       \
                const int row = q * 4 + r;                                       \
                hbw[row * 256 + (((cw * 2 + sub) ^ row) << 4) + l16] = (char)hq; \
            }                                                                    \
        __syncthreads();                                                         \
    }

    for (int i = 0; i < nsteps - 2; i += 2) {
        STEP(xwA, i, "vmcnt(4)");
        STEP(xwB, i + 1, "vmcnt(4)");
    }
    STEP(xwA, nsteps - 2, "vmcnt(4)");
    STEP(xwB, nsteps - 1, "vmcnt(0)");
#undef STEP

    if (s0 + nsteps == T_) {
        #pragma unroll
        for (int sub = 0; sub < 2; ++sub)
            #pragma unroll
            for (int r = 0; r < 4; ++r)
                hfin[((size_t)d * B_ + grp * 16 + q * 4 + r) * H_ + cw * 32 + sub * 16 + l16]
                    = hh8[sub * 4 + r];
    } else {
        float* st = hstate + ((size_t)(bid * 8 + cw) * 64 + lane) * 16;
        #pragma unroll
        for (int j = 0; j < 8; ++j) { st[j] = c8[j]; st[8 + j] = hh8[j]; }
    }
}

// ---------------------------------------------------------------------------
// K4: head (unchanged, proven).
// ---------------------------------------------------------------------------
__global__ __launch_bounds__(256) void k_head(const float* __restrict__ hfin,
        const float* __restrict__ W1, const float* __restrict__ b1,
        const float* __restrict__ W2, const float* __restrict__ b2, float* __restrict__ out)
{
    const int b = blockIdx.x;
    const int tid = threadIdx.x;
    __shared__ float hcat[2 * H_];
    __shared__ float a1[256];
    if (tid < 128) {
        if (tid < 64)
            ((float4*)hcat)[tid] = ((const float4*)(hfin + (size_t)b * H_))[tid];
        else
            ((float4*)(hcat + H_))[tid - 64] = ((const float4*)(hfin + (size_t)(B_ + b) * H_))[tid - 64];
    }
    __syncthreads();
    {
        float s = b1[tid];
        #pragma unroll 4
        for (int k = 0; k < 2 * H_; ++k)
            s += hcat[k] * W1[(size_t)k * 256 + tid];
        a1[tid] = s > 0.f ? s : 0.f;
    }
    __syncthreads();
    if (tid < 32) {
        float s = b2[tid];
        #pragma unroll 4
        for (int j = 0; j < 256; ++j)
            s += a1[j] * W2[(size_t)j * 32 + tid];
        float mx = s;
        #pragma unroll
        for (int o = 16; o > 0; o >>= 1)
            mx = fmaxf(mx, __shfl_xor(mx, o, 32));
        float e = __expf(s - mx);
        float sum = e;
        #pragma unroll
        for (int o = 16; o > 0; o >>= 1)
            sum += __shfl_xor(sum, o, 32);
        out[(size_t)b * 32 + tid] = e / sum;
    }
}

// ---------------------------------------------------------------------------
extern "C" void kernel_launch(void* const* d_in, const int* in_sizes, int n_in,
                              void* d_out, int out_size, void* d_ws, size_t ws_size,
                              hipStream_t stream)
{
    (void)in_sizes; (void)n_in; (void)out_size;
    const int*   tok = (const int*)d_in[0];
    const float* emb = (const float*)d_in[1];
    const float* Wf  = (const float*)d_in[2];
    const float* Uf  = (const float*)d_in[3];
    const float* bf  = (const float*)d_in[4];
    const float* Wb  = (const float*)d_in[5];
    const float* Ub  = (const float*)d_in[6];
    const float* bb  = (const float*)d_in[7];
    const float* W1  = (const float*)d_in[8];
    const float* b1  = (const float*)d_in[9];
    const float* W2  = (const float*)d_in[10];
    const float* b2  = (const float*)d_in[11];
    float* out = (float*)d_out;

    char* ws = (char*)d_ws;
    _Float16* wp   = (_Float16*)(ws);                // 2,097,152 B
    char*     uqp  = (char*)    (ws + 2097152);      //   524,288 B
    float*    scl  = (float*)   (ws + 2621440);      //     8,192 B
    float*    hst  = (float*)   (ws + 2629632);      //   524,288 B
    float*    hfin = (float*)   (ws + 3153920);      //   262,144 B
    _Float16* xwb  = (_Float16*)(ws + 4194304);      // chunkT * 524,288 B

    // chunk the time axis so xwbuf fits whatever workspace we actually have
    size_t avail = ws_size > 4194304 ? ws_size - 4194304 : 0;
    int chunkT = 32;                                  // 21.0 MB total (proven scale)
    if      (avail >= (size_t)512 * 524288) chunkT = 512;   // 272.6 MB
    else if (avail >= (size_t)128 * 524288) chunkT = 128;   //  71.3 MB
    else if (avail >= (size_t) 64 * 524288) chunkT = 64;    //  37.7 MB

    k_perm <<<64, 256, 0, stream>>>(Wf, Uf, Wb, Ub, wp);
    k_permU<<<16, 256, 0, stream>>>(Uf, Ub, uqp, scl);
    for (int s0 = 0; s0 < T_; s0 += chunkT) {
        k_xw <<<chunkT * 2, 256, 0, stream>>>(tok, emb, wp, bf, bb, xwb, s0);
        k_rnn<<<16, 512, 0, stream>>>(xwb, uqp, scl, hst, hfin, s0, chunkT);
    }
    k_head<<<B_, 256, 0, stream>>>(hfin, W1, b1, W2, b2, out);
}